// Round 1
// baseline (4998.376 us; speedup 1.0000x reference)
//
#include <hip/hip_runtime.h>

#define NN 100000
#define NE 600000
#define DD 128
#define NG 512
#define NC 10
#define NL 4

// ---------------- utility kernels ----------------

__global__ __launch_bounds__(256) void k_zero(float* __restrict__ p, int n) {
    int i = blockIdx.x * 256 + threadIdx.x;
    if (i < n) p[i] = 0.f;
}

__global__ __launch_bounds__(256) void k_copy4(const float4* __restrict__ s, float4* __restrict__ d, int n4) {
    int i = blockIdx.x * 256 + threadIdx.x;
    if (i < n4) d[i] = s[i];
}

// ---------------- GIN edge scatter: z[dst] += h[src] ----------------
// one thread per (edge, 4-dim chunk): 32 threads/edge, coalesced row reads.
__global__ __launch_bounds__(256) void k_scatter(const int* __restrict__ src, const int* __restrict__ dst,
                                                 const float* __restrict__ h, float* __restrict__ z) {
    int idx = blockIdx.x * 256 + threadIdx.x;
    int e = idx >> 5;
    if (e >= NE) return;
    int c = (idx & 31) << 2;
    int s = src[e], d = dst[e];
    float4 v = *(const float4*)(h + (size_t)s * DD + c);
    float* zp = z + (size_t)d * DD + c;
    atomicAdd(zp + 0, v.x);
    atomicAdd(zp + 1, v.y);
    atomicAdd(zp + 2, v.z);
    atomicAdd(zp + 3, v.w);
}

// ---------------- GEMM: out = f(Z) @ W + bias, fused column sum/sumsq ----------------
// TRANS: apply v = relu(v*scale[c]+shift[c]) on the input load (BN1+ReLU of the MLP).
// Block: 256 threads, 64 rows x 128 cols. Thread: 8 rows (ty+8r) x 4 cols (tx*4..+3).
template<bool TRANS>
__global__ __launch_bounds__(256) void k_gemm(const float* __restrict__ Z, const float* __restrict__ W,
                                              const float* __restrict__ bias,
                                              const float* __restrict__ sc, const float* __restrict__ sh,
                                              float* __restrict__ out,
                                              float* __restrict__ ssum, float* __restrict__ ssq) {
    __shared__ float zt[64 * DD];  // 32 KB
    const int t = threadIdx.x;
    const int tx = t & 31, ty = t >> 5;
    const int rb = blockIdx.x * 64;
    const int col = tx << 2;

    float4 s4, h4;
    if (TRANS) { s4 = *(const float4*)(sc + col); h4 = *(const float4*)(sh + col); }
    #pragma unroll
    for (int r = 0; r < 8; ++r) {
        int row = ty + (r << 3);
        int g = rb + row;
        float4 v = make_float4(0.f, 0.f, 0.f, 0.f);
        if (g < NN) v = *(const float4*)(Z + (size_t)g * DD + col);
        if (TRANS) {
            v.x = fmaxf(fmaf(v.x, s4.x, h4.x), 0.f);
            v.y = fmaxf(fmaf(v.y, s4.y, h4.y), 0.f);
            v.z = fmaxf(fmaf(v.z, s4.z, h4.z), 0.f);
            v.w = fmaxf(fmaf(v.w, s4.w, h4.w), 0.f);
        }
        *(float4*)(zt + row * DD + col) = v;
    }
    __syncthreads();

    float acc[8][4];
    #pragma unroll
    for (int r = 0; r < 8; ++r)
        #pragma unroll
        for (int c = 0; c < 4; ++c) acc[r][c] = 0.f;

    #pragma unroll 4
    for (int k = 0; k < DD; k += 4) {
        float4 w0 = *(const float4*)(W + (size_t)(k + 0) * DD + col);
        float4 w1 = *(const float4*)(W + (size_t)(k + 1) * DD + col);
        float4 w2 = *(const float4*)(W + (size_t)(k + 2) * DD + col);
        float4 w3 = *(const float4*)(W + (size_t)(k + 3) * DD + col);
        #pragma unroll
        for (int r = 0; r < 8; ++r) {
            float4 zq = *(const float4*)(zt + (ty + (r << 3)) * DD + k);
#define FMA4(zc, wv) \
            acc[r][0] = fmaf(zc, wv.x, acc[r][0]); acc[r][1] = fmaf(zc, wv.y, acc[r][1]); \
            acc[r][2] = fmaf(zc, wv.z, acc[r][2]); acc[r][3] = fmaf(zc, wv.w, acc[r][3]);
            FMA4(zq.x, w0) FMA4(zq.y, w1) FMA4(zq.z, w2) FMA4(zq.w, w3)
#undef FMA4
        }
    }

    float4 bi = *(const float4*)(bias + col);
    float ps[4] = {0.f, 0.f, 0.f, 0.f}, pq[4] = {0.f, 0.f, 0.f, 0.f};
    #pragma unroll
    for (int r = 0; r < 8; ++r) {
        int g = rb + ty + (r << 3);
        if (g < NN) {
            float4 o;
            o.x = acc[r][0] + bi.x; o.y = acc[r][1] + bi.y;
            o.z = acc[r][2] + bi.z; o.w = acc[r][3] + bi.w;
            *(float4*)(out + (size_t)g * DD + col) = o;
            ps[0] += o.x; ps[1] += o.y; ps[2] += o.z; ps[3] += o.w;
            pq[0] += o.x * o.x; pq[1] += o.y * o.y; pq[2] += o.z * o.z; pq[3] += o.w * o.w;
        }
    }
    // block-reduce column partials in LDS (reuse zt), then 2 atomics/col/block
    __syncthreads();
    float* rs = zt;
    float* rq = zt + 8 * DD;
    *(float4*)(rs + ty * DD + col) = make_float4(ps[0], ps[1], ps[2], ps[3]);
    *(float4*)(rq + ty * DD + col) = make_float4(pq[0], pq[1], pq[2], pq[3]);
    __syncthreads();
    if (t < DD) {
        float s = 0.f, q = 0.f;
        #pragma unroll
        for (int y = 0; y < 8; ++y) { s += rs[y * DD + t]; q += rq[y * DD + t]; }
        atomicAdd(ssum + t, s);
        atomicAdd(ssq + t, q);
    }
}

// ---------------- finalize BN stats -> (scale, shift), re-zero accumulators ----------------
__global__ __launch_bounds__(DD) void k_finstats(float* __restrict__ st, const float* __restrict__ g,
                                                 const float* __restrict__ b, float invn) {
    int t = threadIdx.x;
    float m = st[t] * invn;
    float var = st[DD + t] * invn - m * m;
    float s = g[t] * rsqrtf(var + 1e-5f);
    st[2 * DD + t] = s;
    st[3 * DD + t] = b[t] - m * s;
    st[t] = 0.f;
    st[DD + t] = 0.f;
}

// ---------------- outer BN+ReLU, dual write: h_out (B) and z-init for next layer (A, in place) ----------------
__global__ __launch_bounds__(256) void k_bndual(float* __restrict__ A, float* __restrict__ B,
                                                const float* __restrict__ st) {
    int i = blockIdx.x * 256 + threadIdx.x;  // over NN*32 float4
    if (i >= NN * 32) return;
    int c = (i & 31) << 2;
    float4 s4 = *(const float4*)(st + 2 * DD + c);
    float4 h4 = *(const float4*)(st + 3 * DD + c);
    float4 v = *((const float4*)A + i);
    v.x = fmaxf(fmaf(v.x, s4.x, h4.x), 0.f);
    v.y = fmaxf(fmaf(v.y, s4.y, h4.y), 0.f);
    v.z = fmaxf(fmaf(v.z, s4.z, h4.z), 0.f);
    v.w = fmaxf(fmaf(v.w, s4.w, h4.w), 0.f);
    *((float4*)A + i) = v;
    *((float4*)B + i) = v;
}

// ---------------- per-graph pooling (batch is sorted: binary search range, atomic-free) ----------------
__device__ __forceinline__ int lowerb(const int* __restrict__ a, int n, int key) {
    int lo = 0, hi = n;
    while (lo < hi) {
        int mid = (lo + hi) >> 1;
        if (a[mid] < key) lo = mid + 1; else hi = mid;
    }
    return lo;
}

__global__ __launch_bounds__(256) void k_pool(const int* __restrict__ batch, const float* __restrict__ h,
                                              float* __restrict__ pooled) {
    int g = blockIdx.x;
    int t = threadIdx.x;
    int d = t & 127, half = t >> 7;
    int start = lowerb(batch, NN, g);
    int end = lowerb(batch, NN, g + 1);
    float s = 0.f;
    for (int n = start + half; n < end; n += 2) s += h[(size_t)n * DD + d];
    __shared__ float red[256];
    red[t] = s;
    __syncthreads();
    if (t < 128) pooled[(size_t)g * DD + t] = red[t] + red[t + 128];
}

// ---------------- readout: out[g] = log_softmax( sum_i pooled_i[g] @ fc_w[i] + fc_b[i] ) ----------------
__global__ __launch_bounds__(64) void k_readout(const float* __restrict__ pooled, const float* __restrict__ fcw,
                                                const float* __restrict__ fcb, float* __restrict__ out) {
    int g = blockIdx.x, t = threadIdx.x;
    float part[NC];
    #pragma unroll
    for (int c = 0; c < NC; ++c) part[c] = 0.f;
    for (int i = 0; i < NL + 1; ++i) {
        #pragma unroll
        for (int hh = 0; hh < 2; ++hh) {
            int d = t + (hh << 6);
            float v = pooled[((size_t)i * NG + g) * DD + d];
            const float* wr = fcw + ((size_t)i * DD + d) * NC;
            #pragma unroll
            for (int c = 0; c < NC; ++c) part[c] = fmaf(v, wr[c], part[c]);
        }
    }
    #pragma unroll
    for (int off = 32; off >= 1; off >>= 1) {
        #pragma unroll
        for (int c = 0; c < NC; ++c) part[c] += __shfl_down(part[c], off);
    }
    if (t == 0) {
        float y[NC];
        #pragma unroll
        for (int c = 0; c < NC; ++c) {
            float bs = 0.f;
            for (int i = 0; i < NL + 1; ++i) bs += fcb[i * NC + c];
            y[c] = part[c] + bs;
        }
        float m = y[0];
        #pragma unroll
        for (int c = 1; c < NC; ++c) m = fmaxf(m, y[c]);
        float sum = 0.f;
        #pragma unroll
        for (int c = 0; c < NC; ++c) sum += expf(y[c] - m);
        float ls = logf(sum);
        #pragma unroll
        for (int c = 0; c < NC; ++c) out[(size_t)g * NC + c] = y[c] - m - ls;
    }
}

// ---------------- launch ----------------

extern "C" void kernel_launch(void* const* d_in, const int* in_sizes, int n_in,
                              void* d_out, int out_size, void* d_ws, size_t ws_size,
                              hipStream_t stream) {
    const float* x   = (const float*)d_in[0];
    const int*   ei  = (const int*)d_in[1];
    const int*   bat = (const int*)d_in[2];
    const float* w1  = (const float*)d_in[3];
    const float* b1  = (const float*)d_in[4];
    const float* mbg = (const float*)d_in[5];
    const float* mbb = (const float*)d_in[6];
    const float* w2  = (const float*)d_in[7];
    const float* b2  = (const float*)d_in[8];
    const float* bng = (const float*)d_in[9];
    const float* bnb = (const float*)d_in[10];
    const float* fcw = (const float*)d_in[11];
    const float* fcb = (const float*)d_in[12];
    float* out = (float*)d_out;

    float* A      = (float*)d_ws;                 // N x D
    float* B      = A + (size_t)NN * DD;          // N x D
    float* pooled = B + (size_t)NN * DD;          // 5 x 512 x 128
    float* stats  = pooled + (size_t)(NL + 1) * NG * DD;  // sum[128], sq[128], scale[128], shift[128]

    const int* src = ei;
    const int* dst = ei + NE;

    const int nd4 = NN * 32;  // float4 elements per N x D buffer
    hipLaunchKernelGGL(k_zero, dim3(1), dim3(256), 0, stream, stats, 2 * DD);
    hipLaunchKernelGGL(k_copy4, dim3((nd4 + 255) / 256), dim3(256), 0, stream,
                       (const float4*)x, (float4*)A, nd4);

    for (int i = 0; i < NL; ++i) {
        const float* h = (i == 0) ? x : B;
        hipLaunchKernelGGL(k_pool, dim3(NG), dim3(256), 0, stream, bat, h, pooled + (size_t)i * NG * DD);
        hipLaunchKernelGGL(k_scatter, dim3((NE * 32 + 255) / 256), dim3(256), 0, stream, src, dst, h, A);
        hipLaunchKernelGGL((k_gemm<false>), dim3((NN + 63) / 64), dim3(256), 0, stream,
                           A, w1 + (size_t)i * DD * DD, b1 + (size_t)i * DD,
                           nullptr, nullptr, B, stats, stats + DD);
        hipLaunchKernelGGL(k_finstats, dim3(1), dim3(DD), 0, stream, stats, mbg + (size_t)i * DD, mbb + (size_t)i * DD, 1.0f / NN);
        hipLaunchKernelGGL((k_gemm<true>), dim3((NN + 63) / 64), dim3(256), 0, stream,
                           B, w2 + (size_t)i * DD * DD, b2 + (size_t)i * DD,
                           stats + 2 * DD, stats + 3 * DD, A, stats, stats + DD);
        hipLaunchKernelGGL(k_finstats, dim3(1), dim3(DD), 0, stream, stats, bng + (size_t)i * DD, bnb + (size_t)i * DD, 1.0f / NN);
        hipLaunchKernelGGL(k_bndual, dim3((nd4 + 255) / 256), dim3(256), 0, stream, A, B, stats);
    }
    hipLaunchKernelGGL(k_pool, dim3(NG), dim3(256), 0, stream, bat, B, pooled + (size_t)NL * NG * DD);
    hipLaunchKernelGGL(k_readout, dim3(NG), dim3(64), 0, stream, pooled, fcw, fcb, out);
}

// Round 2
// 1209.763 us; speedup vs baseline: 4.1317x; 4.1317x over previous
//
#include <hip/hip_runtime.h>

#define NN 100000
#define NE 600000
#define DD 128
#define NG 512
#define NC 10
#define NL 4

// ---------------- utility kernels ----------------

__global__ __launch_bounds__(256) void k_zero(float* __restrict__ p, int n) {
    int i = blockIdx.x * 256 + threadIdx.x;
    if (i < n) p[i] = 0.f;
}

__global__ __launch_bounds__(256) void k_zeroint(int* __restrict__ p, int n) {
    int i = blockIdx.x * 256 + threadIdx.x;
    if (i < n) p[i] = 0;
}

__global__ __launch_bounds__(256) void k_copyint(const int* __restrict__ s, int* __restrict__ d, int n) {
    int i = blockIdx.x * 256 + threadIdx.x;
    if (i < n) d[i] = s[i];
}

// ---------------- CSR build (once per launch; edges fixed across layers) ----------------

__global__ __launch_bounds__(256) void k_hist(const int* __restrict__ dst, int* __restrict__ deg) {
    int e = blockIdx.x * 256 + threadIdx.x;
    if (e < NE) atomicAdd(&deg[dst[e]], 1);
}

__global__ __launch_bounds__(256) void k_partial(const int* __restrict__ deg, int* __restrict__ part) {
    __shared__ int s[256];
    int t = threadIdx.x;
    int i = blockIdx.x * 256 + t;
    s[t] = (i < NN) ? deg[i] : 0;
    __syncthreads();
    #pragma unroll
    for (int off = 128; off >= 1; off >>= 1) {
        if (t < off) s[t] += s[t + off];
        __syncthreads();
    }
    if (t == 0) part[blockIdx.x] = s[0];
}

// single block of 512 threads: exclusive-scan the block partials (nb <= 512)
__global__ __launch_bounds__(512) void k_scanpart(int* __restrict__ part, int nb) {
    __shared__ int s[512];
    int t = threadIdx.x;
    int v = (t < nb) ? part[t] : 0;
    s[t] = v;
    __syncthreads();
    #pragma unroll
    for (int off = 1; off < 512; off <<= 1) {
        int add = (t >= off) ? s[t - off] : 0;
        __syncthreads();
        s[t] += add;
        __syncthreads();
    }
    if (t < nb) part[t] = s[t] - v;  // exclusive
}

__global__ __launch_bounds__(256) void k_exscan(const int* __restrict__ deg, const int* __restrict__ part,
                                                int* __restrict__ rowofs) {
    __shared__ int s[256];
    int b = blockIdx.x, t = threadIdx.x;
    int i = b * 256 + t;
    int v = (i < NN) ? deg[i] : 0;
    s[t] = v;
    __syncthreads();
    #pragma unroll
    for (int off = 1; off < 256; off <<= 1) {
        int add = (t >= off) ? s[t - off] : 0;
        __syncthreads();
        s[t] += add;
        __syncthreads();
    }
    if (i < NN) rowofs[i] = part[b] + s[t] - v;
    if (i == NN - 1) rowofs[NN] = part[b] + s[t];  // == NE
}

__global__ __launch_bounds__(256) void k_fill(const int* __restrict__ src, const int* __restrict__ dst,
                                              int* __restrict__ cursor, int* __restrict__ csr) {
    int e = blockIdx.x * 256 + threadIdx.x;
    if (e >= NE) return;
    int d = dst[e];
    int pos = atomicAdd(&cursor[d], 1);
    csr[pos] = src[e];
}

// ---------------- GIN aggregate via gather: z[n] = h[n] + sum_{e in CSR[n]} h[csr[e]] ----------------
// 32 lanes per node; each lane owns 4 contiguous dims (float4). Edge reads are
// contiguous 512B rows (LLC-resident), write coalesced, no atomics.
__global__ __launch_bounds__(256) void k_gather(const int* __restrict__ rowofs, const int* __restrict__ csr,
                                                const float* __restrict__ h, float* __restrict__ z) {
    int t = threadIdx.x;
    int n = blockIdx.x * 8 + (t >> 5);
    if (n >= NN) return;
    int col = (t & 31) << 2;
    float4 acc = *(const float4*)(h + (size_t)n * DD + col);
    int start = rowofs[n], end = rowofs[n + 1];
    for (int e = start; e < end; ++e) {
        int s = csr[e];
        float4 v = *(const float4*)(h + (size_t)s * DD + col);
        acc.x += v.x; acc.y += v.y; acc.z += v.z; acc.w += v.w;
    }
    *(float4*)(z + (size_t)n * DD + col) = acc;
}

// ---------------- GEMM: out = f(Z) @ W + bias, fused column sum/sumsq ----------------
template<bool TRANS>
__global__ __launch_bounds__(256) void k_gemm(const float* __restrict__ Z, const float* __restrict__ W,
                                              const float* __restrict__ bias,
                                              const float* __restrict__ sc, const float* __restrict__ sh,
                                              float* __restrict__ out,
                                              float* __restrict__ ssum, float* __restrict__ ssq) {
    __shared__ float zt[64 * DD];  // 32 KB
    const int t = threadIdx.x;
    const int tx = t & 31, ty = t >> 5;
    const int rb = blockIdx.x * 64;
    const int col = tx << 2;

    float4 s4, h4;
    if (TRANS) { s4 = *(const float4*)(sc + col); h4 = *(const float4*)(sh + col); }
    #pragma unroll
    for (int r = 0; r < 8; ++r) {
        int row = ty + (r << 3);
        int g = rb + row;
        float4 v = make_float4(0.f, 0.f, 0.f, 0.f);
        if (g < NN) v = *(const float4*)(Z + (size_t)g * DD + col);
        if (TRANS) {
            v.x = fmaxf(fmaf(v.x, s4.x, h4.x), 0.f);
            v.y = fmaxf(fmaf(v.y, s4.y, h4.y), 0.f);
            v.z = fmaxf(fmaf(v.z, s4.z, h4.z), 0.f);
            v.w = fmaxf(fmaf(v.w, s4.w, h4.w), 0.f);
        }
        *(float4*)(zt + row * DD + col) = v;
    }
    __syncthreads();

    float acc[8][4];
    #pragma unroll
    for (int r = 0; r < 8; ++r)
        #pragma unroll
        for (int c = 0; c < 4; ++c) acc[r][c] = 0.f;

    #pragma unroll 4
    for (int k = 0; k < DD; k += 4) {
        float4 w0 = *(const float4*)(W + (size_t)(k + 0) * DD + col);
        float4 w1 = *(const float4*)(W + (size_t)(k + 1) * DD + col);
        float4 w2 = *(const float4*)(W + (size_t)(k + 2) * DD + col);
        float4 w3 = *(const float4*)(W + (size_t)(k + 3) * DD + col);
        #pragma unroll
        for (int r = 0; r < 8; ++r) {
            float4 zq = *(const float4*)(zt + (ty + (r << 3)) * DD + k);
#define FMA4(zc, wv) \
            acc[r][0] = fmaf(zc, wv.x, acc[r][0]); acc[r][1] = fmaf(zc, wv.y, acc[r][1]); \
            acc[r][2] = fmaf(zc, wv.z, acc[r][2]); acc[r][3] = fmaf(zc, wv.w, acc[r][3]);
            FMA4(zq.x, w0) FMA4(zq.y, w1) FMA4(zq.z, w2) FMA4(zq.w, w3)
#undef FMA4
        }
    }

    float4 bi = *(const float4*)(bias + col);
    float ps[4] = {0.f, 0.f, 0.f, 0.f}, pq[4] = {0.f, 0.f, 0.f, 0.f};
    #pragma unroll
    for (int r = 0; r < 8; ++r) {
        int g = rb + ty + (r << 3);
        if (g < NN) {
            float4 o;
            o.x = acc[r][0] + bi.x; o.y = acc[r][1] + bi.y;
            o.z = acc[r][2] + bi.z; o.w = acc[r][3] + bi.w;
            *(float4*)(out + (size_t)g * DD + col) = o;
            ps[0] += o.x; ps[1] += o.y; ps[2] += o.z; ps[3] += o.w;
            pq[0] += o.x * o.x; pq[1] += o.y * o.y; pq[2] += o.z * o.z; pq[3] += o.w * o.w;
        }
    }
    __syncthreads();
    float* rs = zt;
    float* rq = zt + 8 * DD;
    *(float4*)(rs + ty * DD + col) = make_float4(ps[0], ps[1], ps[2], ps[3]);
    *(float4*)(rq + ty * DD + col) = make_float4(pq[0], pq[1], pq[2], pq[3]);
    __syncthreads();
    if (t < DD) {
        float s = 0.f, q = 0.f;
        #pragma unroll
        for (int y = 0; y < 8; ++y) { s += rs[y * DD + t]; q += rq[y * DD + t]; }
        atomicAdd(ssum + t, s);
        atomicAdd(ssq + t, q);
    }
}

// ---------------- finalize BN stats -> (scale, shift), re-zero accumulators ----------------
__global__ __launch_bounds__(DD) void k_finstats(float* __restrict__ st, const float* __restrict__ g,
                                                 const float* __restrict__ b, float invn) {
    int t = threadIdx.x;
    float m = st[t] * invn;
    float var = st[DD + t] * invn - m * m;
    float s = g[t] * rsqrtf(var + 1e-5f);
    st[2 * DD + t] = s;
    st[3 * DD + t] = b[t] - m * s;
    st[t] = 0.f;
    st[DD + t] = 0.f;
}

// ---------------- outer BN+ReLU: B = relu(A*scale+shift) ----------------
__global__ __launch_bounds__(256) void k_bn(const float* __restrict__ A, float* __restrict__ B,
                                            const float* __restrict__ st) {
    int i = blockIdx.x * 256 + threadIdx.x;  // over NN*32 float4
    if (i >= NN * 32) return;
    int c = (i & 31) << 2;
    float4 s4 = *(const float4*)(st + 2 * DD + c);
    float4 h4 = *(const float4*)(st + 3 * DD + c);
    float4 v = *((const float4*)A + i);
    v.x = fmaxf(fmaf(v.x, s4.x, h4.x), 0.f);
    v.y = fmaxf(fmaf(v.y, s4.y, h4.y), 0.f);
    v.z = fmaxf(fmaf(v.z, s4.z, h4.z), 0.f);
    v.w = fmaxf(fmaf(v.w, s4.w, h4.w), 0.f);
    *((float4*)B + i) = v;
}

// ---------------- per-graph pooling (batch sorted: binary-search range, atomic-free) ----------------
__device__ __forceinline__ int lowerb(const int* __restrict__ a, int n, int key) {
    int lo = 0, hi = n;
    while (lo < hi) {
        int mid = (lo + hi) >> 1;
        if (a[mid] < key) lo = mid + 1; else hi = mid;
    }
    return lo;
}

__global__ __launch_bounds__(256) void k_pool(const int* __restrict__ batch, const float* __restrict__ h,
                                              float* __restrict__ pooled) {
    int g = blockIdx.x;
    int t = threadIdx.x;
    int d = t & 127, half = t >> 7;
    int start = lowerb(batch, NN, g);
    int end = lowerb(batch, NN, g + 1);
    float s = 0.f;
    for (int n = start + half; n < end; n += 2) s += h[(size_t)n * DD + d];
    __shared__ float red[256];
    red[t] = s;
    __syncthreads();
    if (t < 128) pooled[(size_t)g * DD + t] = red[t] + red[t + 128];
}

// ---------------- readout ----------------
__global__ __launch_bounds__(64) void k_readout(const float* __restrict__ pooled, const float* __restrict__ fcw,
                                                const float* __restrict__ fcb, float* __restrict__ out) {
    int g = blockIdx.x, t = threadIdx.x;
    float part[NC];
    #pragma unroll
    for (int c = 0; c < NC; ++c) part[c] = 0.f;
    for (int i = 0; i < NL + 1; ++i) {
        #pragma unroll
        for (int hh = 0; hh < 2; ++hh) {
            int d = t + (hh << 6);
            float v = pooled[((size_t)i * NG + g) * DD + d];
            const float* wr = fcw + ((size_t)i * DD + d) * NC;
            #pragma unroll
            for (int c = 0; c < NC; ++c) part[c] = fmaf(v, wr[c], part[c]);
        }
    }
    #pragma unroll
    for (int off = 32; off >= 1; off >>= 1) {
        #pragma unroll
        for (int c = 0; c < NC; ++c) part[c] += __shfl_down(part[c], off);
    }
    if (t == 0) {
        float y[NC];
        #pragma unroll
        for (int c = 0; c < NC; ++c) {
            float bs = 0.f;
            for (int i = 0; i < NL + 1; ++i) bs += fcb[i * NC + c];
            y[c] = part[c] + bs;
        }
        float m = y[0];
        #pragma unroll
        for (int c = 1; c < NC; ++c) m = fmaxf(m, y[c]);
        float sum = 0.f;
        #pragma unroll
        for (int c = 0; c < NC; ++c) sum += expf(y[c] - m);
        float ls = logf(sum);
        #pragma unroll
        for (int c = 0; c < NC; ++c) out[(size_t)g * NC + c] = y[c] - m - ls;
    }
}

// ---------------- launch ----------------

extern "C" void kernel_launch(void* const* d_in, const int* in_sizes, int n_in,
                              void* d_out, int out_size, void* d_ws, size_t ws_size,
                              hipStream_t stream) {
    const float* x   = (const float*)d_in[0];
    const int*   ei  = (const int*)d_in[1];
    const int*   bat = (const int*)d_in[2];
    const float* w1  = (const float*)d_in[3];
    const float* b1  = (const float*)d_in[4];
    const float* mbg = (const float*)d_in[5];
    const float* mbb = (const float*)d_in[6];
    const float* w2  = (const float*)d_in[7];
    const float* b2  = (const float*)d_in[8];
    const float* bng = (const float*)d_in[9];
    const float* bnb = (const float*)d_in[10];
    const float* fcw = (const float*)d_in[11];
    const float* fcb = (const float*)d_in[12];
    float* out = (float*)d_out;

    float* A      = (float*)d_ws;                          // N x D (z buffer)
    float* B      = A + (size_t)NN * DD;                   // N x D (h buffer)
    float* pooled = B + (size_t)NN * DD;                   // 5 x 512 x 128
    float* stats  = pooled + (size_t)(NL + 1) * NG * DD;   // sum, sq, scale, shift
    int*   deg    = (int*)(stats + 4 * DD);                // NN
    int*   rowofs = deg + NN;                              // NN+1
    int*   part   = rowofs + NN + 1;                       // 512
    int*   cursor = part + 512;                            // NN
    int*   csr    = cursor + NN;                           // NE

    const int* src = ei;
    const int* dst = ei + NE;

    const int nd4 = NN * 32;
    const int nbN = (NN + 255) / 256;   // 391
    const int nbE = (NE + 255) / 256;

    // ---- CSR build (once) ----
    hipLaunchKernelGGL(k_zeroint, dim3(nbN), dim3(256), 0, stream, deg, NN);
    hipLaunchKernelGGL(k_zero, dim3(1), dim3(256), 0, stream, stats, 2 * DD);
    hipLaunchKernelGGL(k_hist, dim3(nbE), dim3(256), 0, stream, dst, deg);
    hipLaunchKernelGGL(k_partial, dim3(nbN), dim3(256), 0, stream, deg, part);
    hipLaunchKernelGGL(k_scanpart, dim3(1), dim3(512), 0, stream, part, nbN);
    hipLaunchKernelGGL(k_exscan, dim3(nbN), dim3(256), 0, stream, deg, part, rowofs);
    hipLaunchKernelGGL(k_copyint, dim3(nbN), dim3(256), 0, stream, rowofs, cursor, NN);
    hipLaunchKernelGGL(k_fill, dim3(nbE), dim3(256), 0, stream, src, dst, cursor, csr);

    // ---- layers ----
    for (int i = 0; i < NL; ++i) {
        const float* h = (i == 0) ? x : B;
        hipLaunchKernelGGL(k_pool, dim3(NG), dim3(256), 0, stream, bat, h, pooled + (size_t)i * NG * DD);
        hipLaunchKernelGGL(k_gather, dim3((NN + 7) / 8), dim3(256), 0, stream, rowofs, csr, h, A);
        hipLaunchKernelGGL((k_gemm<false>), dim3((NN + 63) / 64), dim3(256), 0, stream,
                           A, w1 + (size_t)i * DD * DD, b1 + (size_t)i * DD,
                           nullptr, nullptr, B, stats, stats + DD);
        hipLaunchKernelGGL(k_finstats, dim3(1), dim3(DD), 0, stream, stats, mbg + (size_t)i * DD, mbb + (size_t)i * DD, 1.0f / NN);
        hipLaunchKernelGGL((k_gemm<true>), dim3((NN + 63) / 64), dim3(256), 0, stream,
                           B, w2 + (size_t)i * DD * DD, b2 + (size_t)i * DD,
                           stats + 2 * DD, stats + 3 * DD, A, stats, stats + DD);
        hipLaunchKernelGGL(k_finstats, dim3(1), dim3(DD), 0, stream, stats, bng + (size_t)i * DD, bnb + (size_t)i * DD, 1.0f / NN);
        hipLaunchKernelGGL(k_bn, dim3((nd4 + 255) / 256), dim3(256), 0, stream, A, B, stats);
    }
    hipLaunchKernelGGL(k_pool, dim3(NG), dim3(256), 0, stream, bat, B, pooled + (size_t)NL * NG * DD);
    hipLaunchKernelGGL(k_readout, dim3(NG), dim3(64), 0, stream, pooled, fcw, fcb, out);
}

// Round 3
// 618.827 us; speedup vs baseline: 8.0772x; 1.9549x over previous
//
#include <hip/hip_runtime.h>

#define NN 100000
#define NE 600000
#define DD 128
#define NG 512
#define NC 10
#define NL 4

typedef __attribute__((ext_vector_type(8))) short short8;
typedef __attribute__((ext_vector_type(4))) float f32x4;

__device__ __forceinline__ float b2f(unsigned int u) { return __uint_as_float(u << 16); }
__device__ __forceinline__ unsigned int f2b(float f) {
    unsigned int u = __float_as_uint(f);
    return (u + 0x7fffu + ((u >> 16) & 1u)) >> 16;  // RNE
}
__device__ __forceinline__ void unpack8(uint4 v, float* f) {
    f[0] = b2f(v.x & 0xffffu); f[1] = b2f(v.x >> 16);
    f[2] = b2f(v.y & 0xffffu); f[3] = b2f(v.y >> 16);
    f[4] = b2f(v.z & 0xffffu); f[5] = b2f(v.z >> 16);
    f[6] = b2f(v.w & 0xffffu); f[7] = b2f(v.w >> 16);
}
__device__ __forceinline__ uint4 pack8(const float* f) {
    uint4 v;
    v.x = f2b(f[0]) | (f2b(f[1]) << 16);
    v.y = f2b(f[2]) | (f2b(f[3]) << 16);
    v.z = f2b(f[4]) | (f2b(f[5]) << 16);
    v.w = f2b(f[6]) | (f2b(f[7]) << 16);
    return v;
}

// ---------------- utility ----------------

__global__ __launch_bounds__(256) void k_zero(float* __restrict__ p, int n) {
    int i = blockIdx.x * 256 + threadIdx.x;
    if (i < n) p[i] = 0.f;
}
__global__ __launch_bounds__(256) void k_zeroint(int* __restrict__ p, int n) {
    int i = blockIdx.x * 256 + threadIdx.x;
    if (i < n) p[i] = 0;
}
__global__ __launch_bounds__(256) void k_copyint(const int* __restrict__ s, int* __restrict__ d, int n) {
    int i = blockIdx.x * 256 + threadIdx.x;
    if (i < n) d[i] = s[i];
}

// x (fp32) -> H (bf16)
__global__ __launch_bounds__(256) void k_cvtH(const float* __restrict__ x, ushort* __restrict__ h) {
    int i = blockIdx.x * 256 + threadIdx.x;  // one per 8 elems
    if (i >= NN * DD / 8) return;
    float4 a = ((const float4*)x)[2 * i], b = ((const float4*)x)[2 * i + 1];
    float f[8] = {a.x, a.y, a.z, a.w, b.x, b.y, b.z, b.w};
    ((uint4*)h)[i] = pack8(f);
}

// pack W (fp32 row-major [k][c]) into MFMA B-fragment order, bf16.
// matrix m: 0..3 = w1[l], 4..7 = w2[l-4]. frag id = ((ct*4+kc)*64+lane), 8 bf16 each.
__global__ __launch_bounds__(256) void k_wpack(const float* __restrict__ w1, const float* __restrict__ w2,
                                               ushort* __restrict__ wp) {
    int id = blockIdx.x * 256 + threadIdx.x;  // 16384 total
    int v = id & 63;
    int kc = (id >> 6) & 3;
    int ct = (id >> 8) & 7;
    int m = id >> 11;
    const float* W = (m < 4) ? (w1 + (size_t)m * DD * DD) : (w2 + (size_t)(m - 4) * DD * DD);
    int c = ct * 16 + (v & 15);
    int kbase = kc * 32 + ((v >> 4) << 3);
    ushort* dst = wp + ((size_t)id << 3);
    #pragma unroll
    for (int j = 0; j < 8; ++j) dst[j] = (ushort)f2b(W[(size_t)(kbase + j) * DD + c]);
}

// ---------------- CSR build ----------------

__global__ __launch_bounds__(256) void k_hist(const int* __restrict__ dst, int* __restrict__ deg) {
    int e = blockIdx.x * 256 + threadIdx.x;
    if (e < NE) atomicAdd(&deg[dst[e]], 1);
}
__global__ __launch_bounds__(256) void k_partial(const int* __restrict__ deg, int* __restrict__ part) {
    __shared__ int s[256];
    int t = threadIdx.x;
    int i = blockIdx.x * 256 + t;
    s[t] = (i < NN) ? deg[i] : 0;
    __syncthreads();
    #pragma unroll
    for (int off = 128; off >= 1; off >>= 1) {
        if (t < off) s[t] += s[t + off];
        __syncthreads();
    }
    if (t == 0) part[blockIdx.x] = s[0];
}
__global__ __launch_bounds__(512) void k_scanpart(int* __restrict__ part, int nb) {
    __shared__ int s[512];
    int t = threadIdx.x;
    int v = (t < nb) ? part[t] : 0;
    s[t] = v;
    __syncthreads();
    #pragma unroll
    for (int off = 1; off < 512; off <<= 1) {
        int add = (t >= off) ? s[t - off] : 0;
        __syncthreads();
        s[t] += add;
        __syncthreads();
    }
    if (t < nb) part[t] = s[t] - v;
}
__global__ __launch_bounds__(256) void k_exscan(const int* __restrict__ deg, const int* __restrict__ part,
                                                int* __restrict__ rowofs) {
    __shared__ int s[256];
    int b = blockIdx.x, t = threadIdx.x;
    int i = b * 256 + t;
    int v = (i < NN) ? deg[i] : 0;
    s[t] = v;
    __syncthreads();
    #pragma unroll
    for (int off = 1; off < 256; off <<= 1) {
        int add = (t >= off) ? s[t - off] : 0;
        __syncthreads();
        s[t] += add;
        __syncthreads();
    }
    if (i < NN) rowofs[i] = part[b] + s[t] - v;
    if (i == NN - 1) rowofs[NN] = part[b] + s[t];
}
__global__ __launch_bounds__(256) void k_fill(const int* __restrict__ src, const int* __restrict__ dst,
                                              int* __restrict__ cursor, int* __restrict__ csr) {
    int e = blockIdx.x * 256 + threadIdx.x;
    if (e >= NE) return;
    int d = dst[e];
    int pos = atomicAdd(&cursor[d], 1);
    csr[pos] = src[e];
}

// ---------------- gather (bf16, optional fused BN+ReLU on load) ----------------
// 16 lanes/node, each lane owns one 16B chunk (8 bf16). f32 accumulate.
template<bool BN>
__global__ __launch_bounds__(256) void k_gather(const int* __restrict__ rowofs, const int* __restrict__ csr,
                                                const ushort* __restrict__ h, ushort* __restrict__ z,
                                                const float* __restrict__ scsh) {
    int t = threadIdx.x;
    int n = blockIdx.x * 16 + (t >> 4);
    int cl = t & 15;
    int cb = cl * 8;
    float sc[8], sh[8];
    if (BN) {
        #pragma unroll
        for (int j = 0; j < 8; ++j) { sc[j] = scsh[cb + j]; sh[j] = scsh[DD + cb + j]; }
    }
    float acc[8], f[8];
    uint4 v = ((const uint4*)h)[(size_t)n * 16 + cl];
    unpack8(v, f);
    #pragma unroll
    for (int j = 0; j < 8; ++j)
        acc[j] = BN ? fmaxf(fmaf(f[j], sc[j], sh[j]), 0.f) : f[j];
    int start = rowofs[n], end = rowofs[n + 1];
    for (int e = start; e < end; ++e) {
        int s = csr[e];
        v = ((const uint4*)h)[(size_t)s * 16 + cl];
        unpack8(v, f);
        #pragma unroll
        for (int j = 0; j < 8; ++j)
            acc[j] += BN ? fmaxf(fmaf(f[j], sc[j], sh[j]), 0.f) : f[j];
    }
    ((uint4*)z)[(size_t)n * 16 + cl] = pack8(acc);
}

// ---------------- MFMA GEMM: out = f(in) @ W + bias, fused column stats ----------------
// block: 256 thr = 4 waves (2 row x 2 col), tile 128x128, K=128.
// LDS A-tile bf16 with XOR swizzle (byte ^= (row&7)<<4). W pre-packed B-frags in regs.
// TRANS: input transformed by relu(v*scale+shift) during staging.
template<bool TRANS>
__global__ __launch_bounds__(256) void k_mm(const ushort* __restrict__ in, const ushort* __restrict__ wp,
                                            const float* __restrict__ bias, const float* __restrict__ scsh,
                                            ushort* __restrict__ outp,
                                            float* __restrict__ ssum, float* __restrict__ ssq) {
    __shared__ __align__(16) char lds[32768];
    const int t = threadIdx.x;
    const int lane = t & 63;
    const int wid = t >> 6;
    const int wr = wid >> 1, wc = wid & 1;
    const int rb = blockIdx.x * 128;
    const int rep = blockIdx.x & 7;

    // B fragments from packed W (global, L2-hit; coalesced 16B/lane)
    short8 bfrag[4][4];
    #pragma unroll
    for (int ct = 0; ct < 4; ++ct)
        #pragma unroll
        for (int kc = 0; kc < 4; ++kc)
            bfrag[ct][kc] = *(const short8*)(wp + (size_t)((((wc * 4 + ct) * 4 + kc) * 64 + lane) << 3));

    // stage A tile -> LDS (swizzled)
    #pragma unroll
    for (int i = 0; i < 8; ++i) {
        int c = i * 256 + t;       // chunk id 0..2047
        int row = c >> 4;
        int g = rb + row;
        uint4 v = make_uint4(0, 0, 0, 0);
        if (g < NN) {
            v = *((const uint4*)in + (size_t)g * 16 + (c & 15));
            if (TRANS) {
                float f[8];
                unpack8(v, f);
                int cb = (c & 15) * 8;
                #pragma unroll
                for (int j = 0; j < 8; ++j) f[j] = fmaxf(fmaf(f[j], scsh[cb + j], scsh[DD + cb + j]), 0.f);
                v = pack8(f);
            }
        }
        *(uint4*)(lds + ((c * 16) ^ ((row & 7) << 4))) = v;
    }
    __syncthreads();

    f32x4 acc[4][4];
    #pragma unroll
    for (int rt = 0; rt < 4; ++rt)
        #pragma unroll
        for (int ct = 0; ct < 4; ++ct) acc[rt][ct] = (f32x4){0.f, 0.f, 0.f, 0.f};

    #pragma unroll
    for (int kc = 0; kc < 4; ++kc) {
        #pragma unroll
        for (int rt = 0; rt < 4; ++rt) {
            int row = wr * 64 + rt * 16 + (lane & 15);
            int off = (row * 256 + ((kc * 32 + ((lane >> 4) << 3)) << 1)) ^ ((row & 7) << 4);
            short8 af = *(const short8*)(lds + off);
            #pragma unroll
            for (int ct = 0; ct < 4; ++ct)
                acc[rt][ct] = __builtin_amdgcn_mfma_f32_16x16x32_bf16(af, bfrag[ct][kc], acc[rt][ct], 0, 0, 0);
        }
    }
    __syncthreads();

    // epilogue: bias + stats partials + bf16 into LDS (transpose staging)
    float ps[4] = {0.f, 0.f, 0.f, 0.f}, pq[4] = {0.f, 0.f, 0.f, 0.f};
    const int lrow = (lane >> 4) << 2;
    const int lcol = lane & 15;
    #pragma unroll
    for (int rt = 0; rt < 4; ++rt) {
        #pragma unroll
        for (int ct = 0; ct < 4; ++ct) {
            int col = wc * 64 + ct * 16 + lcol;
            float bi = bias[col];
            f32x4 a = acc[rt][ct];
            #pragma unroll
            for (int r = 0; r < 4; ++r) {
                int row = wr * 64 + rt * 16 + lrow + r;
                float v = a[r] + bi;
                if (rb + row < NN) { ps[ct] += v; pq[ct] += v * v; }
                *(ushort*)(lds + ((row * 256 + col * 2) ^ ((row & 7) << 4))) = (ushort)f2b(v);
            }
        }
    }
    // column stats: reduce across the 4 row-groups of the wave, then 8-replica atomics
    #pragma unroll
    for (int ct = 0; ct < 4; ++ct) {
        float s = ps[ct], q = pq[ct];
        s += __shfl_xor(s, 16); s += __shfl_xor(s, 32);
        q += __shfl_xor(q, 16); q += __shfl_xor(q, 32);
        if (lane < 16) {
            int col = wc * 64 + ct * 16 + lane;
            atomicAdd(ssum + rep * DD + col, s);
            atomicAdd(ssq + rep * DD + col, q);
        }
    }
    __syncthreads();
    // coalesced bf16 store
    #pragma unroll
    for (int i = 0; i < 8; ++i) {
        int c = i * 256 + t;
        int row = c >> 4;
        int g = rb + row;
        if (g < NN) {
            uint4 v = *(const uint4*)(lds + ((c * 16) ^ ((row & 7) << 4)));
            ((uint4*)outp)[(size_t)g * 16 + (c & 15)] = v;
        }
    }
}

// ---------------- BN stats -> (scale, shift), re-zero replicas ----------------
__global__ __launch_bounds__(DD) void k_finstats(float* __restrict__ ssum, float* __restrict__ ssq,
                                                 float* __restrict__ dst,
                                                 const float* __restrict__ g, const float* __restrict__ b) {
    int t = threadIdx.x;
    float s = 0.f, q = 0.f;
    #pragma unroll
    for (int r = 0; r < 8; ++r) {
        s += ssum[r * DD + t]; q += ssq[r * DD + t];
        ssum[r * DD + t] = 0.f; ssq[r * DD + t] = 0.f;
    }
    const float invn = 1.0f / NN;
    float m = s * invn;
    float var = q * invn - m * m;
    float sc = g[t] * rsqrtf(var + 1e-5f);
    dst[t] = sc;
    dst[DD + t] = b[t] - m * sc;
}

// ---------------- per-graph pooling (bf16 input, optional fused BN+ReLU) ----------------
__device__ __forceinline__ int lowerb(const int* __restrict__ a, int n, int key) {
    int lo = 0, hi = n;
    while (lo < hi) {
        int mid = (lo + hi) >> 1;
        if (a[mid] < key) lo = mid + 1; else hi = mid;
    }
    return lo;
}

template<bool BN>
__global__ __launch_bounds__(256) void k_pool(const int* __restrict__ batch, const ushort* __restrict__ h,
                                              float* __restrict__ pooled, const float* __restrict__ scsh) {
    int g = blockIdx.x;
    int t = threadIdx.x;
    int d = t & 127, half = t >> 7;
    float sc = 0.f, sh = 0.f;
    if (BN) { sc = scsh[d]; sh = scsh[DD + d]; }
    int start = lowerb(batch, NN, g);
    int end = lowerb(batch, NN, g + 1);
    float s = 0.f;
    for (int n = start + half; n < end; n += 2) {
        float v = b2f((unsigned int)h[(size_t)n * DD + d]);
        if (BN) v = fmaxf(fmaf(v, sc, sh), 0.f);
        s += v;
    }
    __shared__ float red[256];
    red[t] = s;
    __syncthreads();
    if (t < 128) pooled[(size_t)g * DD + t] = red[t] + red[t + 128];
}

// ---------------- readout ----------------
__global__ __launch_bounds__(64) void k_readout(const float* __restrict__ pooled, const float* __restrict__ fcw,
                                                const float* __restrict__ fcb, float* __restrict__ out) {
    int g = blockIdx.x, t = threadIdx.x;
    float part[NC];
    #pragma unroll
    for (int c = 0; c < NC; ++c) part[c] = 0.f;
    for (int i = 0; i < NL + 1; ++i) {
        #pragma unroll
        for (int hh = 0; hh < 2; ++hh) {
            int d = t + (hh << 6);
            float v = pooled[((size_t)i * NG + g) * DD + d];
            const float* wr = fcw + ((size_t)i * DD + d) * NC;
            #pragma unroll
            for (int c = 0; c < NC; ++c) part[c] = fmaf(v, wr[c], part[c]);
        }
    }
    #pragma unroll
    for (int off = 32; off >= 1; off >>= 1) {
        #pragma unroll
        for (int c = 0; c < NC; ++c) part[c] += __shfl_down(part[c], off);
    }
    if (t == 0) {
        float y[NC];
        #pragma unroll
        for (int c = 0; c < NC; ++c) {
            float bs = 0.f;
            for (int i = 0; i < NL + 1; ++i) bs += fcb[i * NC + c];
            y[c] = part[c] + bs;
        }
        float m = y[0];
        #pragma unroll
        for (int c = 1; c < NC; ++c) m = fmaxf(m, y[c]);
        float sum = 0.f;
        #pragma unroll
        for (int c = 0; c < NC; ++c) sum += expf(y[c] - m);
        float ls = logf(sum);
        #pragma unroll
        for (int c = 0; c < NC; ++c) out[(size_t)g * NC + c] = y[c] - m - ls;
    }
}

// ---------------- launch ----------------

extern "C" void kernel_launch(void* const* d_in, const int* in_sizes, int n_in,
                              void* d_out, int out_size, void* d_ws, size_t ws_size,
                              hipStream_t stream) {
    const float* x   = (const float*)d_in[0];
    const int*   ei  = (const int*)d_in[1];
    const int*   bat = (const int*)d_in[2];
    const float* w1  = (const float*)d_in[3];
    const float* b1  = (const float*)d_in[4];
    const float* mbg = (const float*)d_in[5];
    const float* mbb = (const float*)d_in[6];
    const float* w2  = (const float*)d_in[7];
    const float* b2  = (const float*)d_in[8];
    const float* bng = (const float*)d_in[9];
    const float* bnb = (const float*)d_in[10];
    const float* fcw = (const float*)d_in[11];
    const float* fcb = (const float*)d_in[12];
    float* out = (float*)d_out;

    ushort* H  = (ushort*)d_ws;                 // N x D bf16 (x at start; overwritten by gemm2)
    ushort* Z  = H + (size_t)NN * DD;           // N x D bf16 (gather out)
    ushort* Y1 = Z + (size_t)NN * DD;           // N x D bf16 (gemm1 out)
    ushort* WP = Y1 + (size_t)NN * DD;          // 8 * 16384 bf16 packed W frags
    float* pooled = (float*)(WP + 8 * 16384);   // 5 x 512 x 128
    float* scsh   = pooled + (size_t)(NL + 1) * NG * DD;  // NL x 2 x (2*DD)
    float* ssum   = scsh + NL * 2 * 2 * DD;     // 8 x 128
    float* ssq    = ssum + 8 * DD;              // 8 x 128
    int* deg    = (int*)(ssq + 8 * DD);
    int* rowofs = deg + NN;
    int* part   = rowofs + NN + 1;
    int* cursor = part + 512;
    int* csr    = cursor + NN;

    const int* src = ei;
    const int* dst = ei + NE;
    const int nbN = (NN + 255) / 256;
    const int nbE = (NE + 255) / 256;

    hipLaunchKernelGGL(k_cvtH, dim3(NN * DD / 8 / 256 + 1), dim3(256), 0, stream, x, H);
    hipLaunchKernelGGL(k_zero, dim3(8), dim3(256), 0, stream, ssum, 16 * DD);  // ssum+ssq contiguous
    hipLaunchKernelGGL(k_zeroint, dim3(nbN), dim3(256), 0, stream, deg, NN);
    hipLaunchKernelGGL(k_hist, dim3(nbE), dim3(256), 0, stream, dst, deg);
    hipLaunchKernelGGL(k_partial, dim3(nbN), dim3(256), 0, stream, deg, part);
    hipLaunchKernelGGL(k_scanpart, dim3(1), dim3(512), 0, stream, part, nbN);
    hipLaunchKernelGGL(k_exscan, dim3(nbN), dim3(256), 0, stream, deg, part, rowofs);
    hipLaunchKernelGGL(k_copyint, dim3(nbN), dim3(256), 0, stream, rowofs, cursor, NN);
    hipLaunchKernelGGL(k_fill, dim3(nbE), dim3(256), 0, stream, src, dst, cursor, csr);
    hipLaunchKernelGGL(k_wpack, dim3(64), dim3(256), 0, stream, w1, w2, WP);

    const int gmm = (NN + 127) / 128;  // 782
    for (int i = 0; i < NL; ++i) {
        float* slot_mlp = scsh + (size_t)(i * 2 + 0) * 2 * DD;
        float* slot_out = scsh + (size_t)(i * 2 + 1) * 2 * DD;
        if (i == 0) {
            hipLaunchKernelGGL((k_pool<false>), dim3(NG), dim3(256), 0, stream, bat, H, pooled, (const float*)nullptr);
            hipLaunchKernelGGL((k_gather<false>), dim3(NN / 16), dim3(256), 0, stream, rowofs, csr, H, Z, (const float*)nullptr);
        } else {
            const float* bnp = scsh + (size_t)((i - 1) * 2 + 1) * 2 * DD;
            hipLaunchKernelGGL((k_pool<true>), dim3(NG), dim3(256), 0, stream, bat, H, pooled + (size_t)i * NG * DD, bnp);
            hipLaunchKernelGGL((k_gather<true>), dim3(NN / 16), dim3(256), 0, stream, rowofs, csr, H, Z, bnp);
        }
        hipLaunchKernelGGL((k_mm<false>), dim3(gmm), dim3(256), 0, stream,
                           Z, WP + (size_t)i * 16384, b1 + (size_t)i * DD, (const float*)nullptr, Y1, ssum, ssq);
        hipLaunchKernelGGL(k_finstats, dim3(1), dim3(DD), 0, stream, ssum, ssq, slot_mlp, mbg + (size_t)i * DD, mbb + (size_t)i * DD);
        hipLaunchKernelGGL((k_mm<true>), dim3(gmm), dim3(256), 0, stream,
                           Y1, WP + (size_t)(4 + i) * 16384, b2 + (size_t)i * DD, slot_mlp, H, ssum, ssq);
        hipLaunchKernelGGL(k_finstats, dim3(1), dim3(DD), 0, stream, ssum, ssq, slot_out, bng + (size_t)i * DD, bnb + (size_t)i * DD);
    }
    hipLaunchKernelGGL((k_pool<true>), dim3(NG), dim3(256), 0, stream, bat, H,
                       pooled + (size_t)NL * NG * DD, scsh + (size_t)(3 * 2 + 1) * 2 * DD);
    hipLaunchKernelGGL(k_readout, dim3(NG), dim3(64), 0, stream, pooled, fcw, fcb, out);
}

// Round 4
// 482.710 us; speedup vs baseline: 10.3548x; 1.2820x over previous
//
#include <hip/hip_runtime.h>

#define NN 100000
#define NE 600000
#define DD 128
#define NG 512
#define NC 10
#define NL 4

typedef __attribute__((ext_vector_type(8))) short short8;
typedef __attribute__((ext_vector_type(4))) float f32x4;

__device__ __forceinline__ float b2f(unsigned int u) { return __uint_as_float(u << 16); }
__device__ __forceinline__ unsigned int f2b(float f) {
    unsigned int u = __float_as_uint(f);
    return (u + 0x7fffu + ((u >> 16) & 1u)) >> 16;  // RNE
}
__device__ __forceinline__ void unpack8(uint4 v, float* f) {
    f[0] = b2f(v.x & 0xffffu); f[1] = b2f(v.x >> 16);
    f[2] = b2f(v.y & 0xffffu); f[3] = b2f(v.y >> 16);
    f[4] = b2f(v.z & 0xffffu); f[5] = b2f(v.z >> 16);
    f[6] = b2f(v.w & 0xffffu); f[7] = b2f(v.w >> 16);
}
__device__ __forceinline__ uint4 pack8(const float* f) {
    uint4 v;
    v.x = f2b(f[0]) | (f2b(f[1]) << 16);
    v.y = f2b(f[2]) | (f2b(f[3]) << 16);
    v.z = f2b(f[4]) | (f2b(f[5]) << 16);
    v.w = f2b(f[6]) | (f2b(f[7]) << 16);
    return v;
}

// ---------------- utility ----------------

__global__ __launch_bounds__(256) void k_zero(float* __restrict__ p, int n) {
    int i = blockIdx.x * 256 + threadIdx.x;
    if (i < n) p[i] = 0.f;
}
__global__ __launch_bounds__(256) void k_zeroint(int* __restrict__ p, int n) {
    int i = blockIdx.x * 256 + threadIdx.x;
    if (i < n) p[i] = 0;
}
__global__ __launch_bounds__(256) void k_copyint(const int* __restrict__ s, int* __restrict__ d, int n) {
    int i = blockIdx.x * 256 + threadIdx.x;
    if (i < n) d[i] = s[i];
}

// x (fp32) -> H (bf16)
__global__ __launch_bounds__(256) void k_cvtH(const float* __restrict__ x, ushort* __restrict__ h) {
    int i = blockIdx.x * 256 + threadIdx.x;  // one per 8 elems
    if (i >= NN * DD / 8) return;
    float4 a = ((const float4*)x)[2 * i], b = ((const float4*)x)[2 * i + 1];
    float f[8] = {a.x, a.y, a.z, a.w, b.x, b.y, b.z, b.w};
    ((uint4*)h)[i] = pack8(f);
}

// pack W (fp32 row-major [k][c]) into MFMA B-fragment order, bf16.
__global__ __launch_bounds__(256) void k_wpack(const float* __restrict__ w1, const float* __restrict__ w2,
                                               ushort* __restrict__ wp) {
    int id = blockIdx.x * 256 + threadIdx.x;  // 16384 total
    int v = id & 63;
    int kc = (id >> 6) & 3;
    int ct = (id >> 8) & 7;
    int m = id >> 11;
    const float* W = (m < 4) ? (w1 + (size_t)m * DD * DD) : (w2 + (size_t)(m - 4) * DD * DD);
    int c = ct * 16 + (v & 15);
    int kbase = kc * 32 + ((v >> 4) << 3);
    ushort* dst = wp + ((size_t)id << 3);
    #pragma unroll
    for (int j = 0; j < 8; ++j) dst[j] = (ushort)f2b(W[(size_t)(kbase + j) * DD + c]);
}

// ---------------- CSR build ----------------

__global__ __launch_bounds__(256) void k_hist(const int* __restrict__ dst, int* __restrict__ deg) {
    int e = blockIdx.x * 256 + threadIdx.x;
    if (e < NE) atomicAdd(&deg[dst[e]], 1);
}
__global__ __launch_bounds__(256) void k_partial(const int* __restrict__ deg, int* __restrict__ part) {
    __shared__ int s[256];
    int t = threadIdx.x;
    int i = blockIdx.x * 256 + t;
    s[t] = (i < NN) ? deg[i] : 0;
    __syncthreads();
    #pragma unroll
    for (int off = 128; off >= 1; off >>= 1) {
        if (t < off) s[t] += s[t + off];
        __syncthreads();
    }
    if (t == 0) part[blockIdx.x] = s[0];
}
__global__ __launch_bounds__(512) void k_scanpart(int* __restrict__ part, int nb) {
    __shared__ int s[512];
    int t = threadIdx.x;
    int v = (t < nb) ? part[t] : 0;
    s[t] = v;
    __syncthreads();
    #pragma unroll
    for (int off = 1; off < 512; off <<= 1) {
        int add = (t >= off) ? s[t - off] : 0;
        __syncthreads();
        s[t] += add;
        __syncthreads();
    }
    if (t < nb) part[t] = s[t] - v;
}
__global__ __launch_bounds__(256) void k_exscan(const int* __restrict__ deg, const int* __restrict__ part,
                                                int* __restrict__ rowofs) {
    __shared__ int s[256];
    int b = blockIdx.x, t = threadIdx.x;
    int i = b * 256 + t;
    int v = (i < NN) ? deg[i] : 0;
    s[t] = v;
    __syncthreads();
    #pragma unroll
    for (int off = 1; off < 256; off <<= 1) {
        int add = (t >= off) ? s[t - off] : 0;
        __syncthreads();
        s[t] += add;
        __syncthreads();
    }
    if (i < NN) rowofs[i] = part[b] + s[t] - v;
    if (i == NN - 1) rowofs[NN] = part[b] + s[t];
}
__global__ __launch_bounds__(256) void k_fill(const int* __restrict__ src, const int* __restrict__ dst,
                                              int* __restrict__ cursor, int* __restrict__ csr) {
    int e = blockIdx.x * 256 + threadIdx.x;
    if (e >= NE) return;
    int d = dst[e];
    int pos = atomicAdd(&cursor[d], 1);
    csr[pos] = src[e];
}

// ---------------- gather (bf16, optional fused BN+ReLU on load) ----------------
template<bool BN>
__global__ __launch_bounds__(256) void k_gather(const int* __restrict__ rowofs, const int* __restrict__ csr,
                                                const ushort* __restrict__ h, ushort* __restrict__ z,
                                                const float* __restrict__ scsh) {
    int t = threadIdx.x;
    int n = blockIdx.x * 16 + (t >> 4);
    int cl = t & 15;
    int cb = cl * 8;
    float sc[8], sh[8];
    if (BN) {
        #pragma unroll
        for (int j = 0; j < 8; ++j) { sc[j] = scsh[cb + j]; sh[j] = scsh[DD + cb + j]; }
    }
    float acc[8], f[8];
    uint4 v = ((const uint4*)h)[(size_t)n * 16 + cl];
    unpack8(v, f);
    #pragma unroll
    for (int j = 0; j < 8; ++j)
        acc[j] = BN ? fmaxf(fmaf(f[j], sc[j], sh[j]), 0.f) : f[j];
    int start = rowofs[n], end = rowofs[n + 1];
    for (int e = start; e < end; ++e) {
        int s = csr[e];
        v = ((const uint4*)h)[(size_t)s * 16 + cl];
        unpack8(v, f);
        #pragma unroll
        for (int j = 0; j < 8; ++j)
            acc[j] += BN ? fmaxf(fmaf(f[j], sc[j], sh[j]), 0.f) : f[j];
    }
    ((uint4*)z)[(size_t)n * 16 + cl] = pack8(acc);
}

// ---------------- MFMA GEMM: out = f(in) @ W + bias, fused column stats ----------------
template<bool TRANS>
__global__ __launch_bounds__(256) void k_mm(const ushort* __restrict__ in, const ushort* __restrict__ wp,
                                            const float* __restrict__ bias, const float* __restrict__ scsh,
                                            ushort* __restrict__ outp,
                                            float* __restrict__ ssum, float* __restrict__ ssq) {
    __shared__ __align__(16) char lds[32768];
    const int t = threadIdx.x;
    const int lane = t & 63;
    const int wid = t >> 6;
    const int wr = wid >> 1, wc = wid & 1;
    const int rb = blockIdx.x * 128;
    const int rep = blockIdx.x & 7;

    short8 bfrag[4][4];
    #pragma unroll
    for (int ct = 0; ct < 4; ++ct)
        #pragma unroll
        for (int kc = 0; kc < 4; ++kc)
            bfrag[ct][kc] = *(const short8*)(wp + (size_t)((((wc * 4 + ct) * 4 + kc) * 64 + lane) << 3));

    #pragma unroll
    for (int i = 0; i < 8; ++i) {
        int c = i * 256 + t;       // chunk id 0..2047
        int row = c >> 4;
        int g = rb + row;
        uint4 v = make_uint4(0, 0, 0, 0);
        if (g < NN) {
            v = *((const uint4*)in + (size_t)g * 16 + (c & 15));
            if (TRANS) {
                float f[8];
                unpack8(v, f);
                int cb = (c & 15) * 8;
                #pragma unroll
                for (int j = 0; j < 8; ++j) f[j] = fmaxf(fmaf(f[j], scsh[cb + j], scsh[DD + cb + j]), 0.f);
                v = pack8(f);
            }
        }
        *(uint4*)(lds + ((c * 16) ^ ((row & 7) << 4))) = v;
    }
    __syncthreads();

    f32x4 acc[4][4];
    #pragma unroll
    for (int rt = 0; rt < 4; ++rt)
        #pragma unroll
        for (int ct = 0; ct < 4; ++ct) acc[rt][ct] = (f32x4){0.f, 0.f, 0.f, 0.f};

    #pragma unroll
    for (int kc = 0; kc < 4; ++kc) {
        #pragma unroll
        for (int rt = 0; rt < 4; ++rt) {
            int row = wr * 64 + rt * 16 + (lane & 15);
            int off = (row * 256 + ((kc * 32 + ((lane >> 4) << 3)) << 1)) ^ ((row & 7) << 4);
            short8 af = *(const short8*)(lds + off);
            #pragma unroll
            for (int ct = 0; ct < 4; ++ct)
                acc[rt][ct] = __builtin_amdgcn_mfma_f32_16x16x32_bf16(af, bfrag[ct][kc], acc[rt][ct], 0, 0, 0);
        }
    }
    __syncthreads();

    float ps[4] = {0.f, 0.f, 0.f, 0.f}, pq[4] = {0.f, 0.f, 0.f, 0.f};
    const int lrow = (lane >> 4) << 2;
    const int lcol = lane & 15;
    #pragma unroll
    for (int rt = 0; rt < 4; ++rt) {
        #pragma unroll
        for (int ct = 0; ct < 4; ++ct) {
            int col = wc * 64 + ct * 16 + lcol;
            float bi = bias[col];
            f32x4 a = acc[rt][ct];
            #pragma unroll
            for (int r = 0; r < 4; ++r) {
                int row = wr * 64 + rt * 16 + lrow + r;
                float v = a[r] + bi;
                if (rb + row < NN) { ps[ct] += v; pq[ct] += v * v; }
                *(ushort*)(lds + ((row * 256 + col * 2) ^ ((row & 7) << 4))) = (ushort)f2b(v);
            }
        }
    }
    #pragma unroll
    for (int ct = 0; ct < 4; ++ct) {
        float s = ps[ct], q = pq[ct];
        s += __shfl_xor(s, 16); s += __shfl_xor(s, 32);
        q += __shfl_xor(q, 16); q += __shfl_xor(q, 32);
        if (lane < 16) {
            int col = wc * 64 + ct * 16 + lane;
            atomicAdd(ssum + rep * DD + col, s);
            atomicAdd(ssq + rep * DD + col, q);
        }
    }
    __syncthreads();
    #pragma unroll
    for (int i = 0; i < 8; ++i) {
        int c = i * 256 + t;
        int row = c >> 4;
        int g = rb + row;
        if (g < NN) {
            uint4 v = *(const uint4*)(lds + ((c * 16) ^ ((row & 7) << 4)));
            ((uint4*)outp)[(size_t)g * 16 + (c & 15)] = v;
        }
    }
}

// ---------------- BN stats -> (scale, shift), re-zero replicas ----------------
__global__ __launch_bounds__(DD) void k_finstats(float* __restrict__ ssum, float* __restrict__ ssq,
                                                 float* __restrict__ dst,
                                                 const float* __restrict__ g, const float* __restrict__ b) {
    int t = threadIdx.x;
    float s = 0.f, q = 0.f;
    #pragma unroll
    for (int r = 0; r < 8; ++r) {
        s += ssum[r * DD + t]; q += ssq[r * DD + t];
        ssum[r * DD + t] = 0.f; ssq[r * DD + t] = 0.f;
    }
    const float invn = 1.0f / NN;
    float m = s * invn;
    float var = q * invn - m * m;
    float sc = g[t] * rsqrtf(var + 1e-5f);
    dst[t] = sc;
    dst[DD + t] = b[t] - m * sc;
}

// ---------------- per-graph pooling: vectorized, 16 lanes x 16 row-slots ----------------
__device__ __forceinline__ int lowerb(const int* __restrict__ a, int n, int key) {
    int lo = 0, hi = n;
    while (lo < hi) {
        int mid = (lo + hi) >> 1;
        if (a[mid] < key) lo = mid + 1; else hi = mid;
    }
    return lo;
}

template<bool BN>
__global__ __launch_bounds__(256) void k_pool(const int* __restrict__ batch, const ushort* __restrict__ h,
                                              float* __restrict__ pooled, const float* __restrict__ scsh) {
    int g = blockIdx.x;
    int t = threadIdx.x;
    int cl = t & 15;   // col chunk (8 bf16)
    int rs = t >> 4;   // row slot 0..15
    int cb = cl * 8;
    float sc[8], sh[8];
    if (BN) {
        #pragma unroll
        for (int j = 0; j < 8; ++j) { sc[j] = scsh[cb + j]; sh[j] = scsh[DD + cb + j]; }
    }
    int start = lowerb(batch, NN, g);
    int end = lowerb(batch, NN, g + 1);
    float acc[8];
    #pragma unroll
    for (int j = 0; j < 8; ++j) acc[j] = 0.f;
    for (int n = start + rs; n < end; n += 16) {
        uint4 v = ((const uint4*)h)[(size_t)n * 16 + cl];
        float f[8];
        unpack8(v, f);
        #pragma unroll
        for (int j = 0; j < 8; ++j)
            acc[j] += BN ? fmaxf(fmaf(f[j], sc[j], sh[j]), 0.f) : f[j];
    }
    __shared__ float red[16 * DD];
    #pragma unroll
    for (int j = 0; j < 8; j += 4)
        *(float4*)(red + rs * DD + cb + j) = make_float4(acc[j], acc[j + 1], acc[j + 2], acc[j + 3]);
    __syncthreads();
    #pragma unroll
    for (int off = 8; off >= 1; off >>= 1) {
        if (rs < off) {
            #pragma unroll
            for (int j = 0; j < 8; j += 4) {
                float4 a = *(float4*)(red + rs * DD + cb + j);
                float4 b = *(float4*)(red + (rs + off) * DD + cb + j);
                a.x += b.x; a.y += b.y; a.z += b.z; a.w += b.w;
                *(float4*)(red + rs * DD + cb + j) = a;
            }
        }
        __syncthreads();
    }
    if (rs == 0) {
        #pragma unroll
        for (int j = 0; j < 8; j += 4)
            *(float4*)(pooled + (size_t)g * DD + cb + j) = *(float4*)(red + cb + j);
    }
}

// ---------------- readout ----------------
__global__ __launch_bounds__(64) void k_readout(const float* __restrict__ pooled, const float* __restrict__ fcw,
                                                const float* __restrict__ fcb, float* __restrict__ out) {
    int g = blockIdx.x, t = threadIdx.x;
    float part[NC];
    #pragma unroll
    for (int c = 0; c < NC; ++c) part[c] = 0.f;
    for (int i = 0; i < NL + 1; ++i) {
        #pragma unroll
        for (int hh = 0; hh < 2; ++hh) {
            int d = t + (hh << 6);
            float v = pooled[((size_t)i * NG + g) * DD + d];
            const float* wr = fcw + ((size_t)i * DD + d) * NC;
            #pragma unroll
            for (int c = 0; c < NC; ++c) part[c] = fmaf(v, wr[c], part[c]);
        }
    }
    #pragma unroll
    for (int off = 32; off >= 1; off >>= 1) {
        #pragma unroll
        for (int c = 0; c < NC; ++c) part[c] += __shfl_down(part[c], off);
    }
    if (t == 0) {
        float y[NC];
        #pragma unroll
        for (int c = 0; c < NC; ++c) {
            float bs = 0.f;
            for (int i = 0; i < NL + 1; ++i) bs += fcb[i * NC + c];
            y[c] = part[c] + bs;
        }
        float m = y[0];
        #pragma unroll
        for (int c = 1; c < NC; ++c) m = fmaxf(m, y[c]);
        float sum = 0.f;
        #pragma unroll
        for (int c = 0; c < NC; ++c) sum += expf(y[c] - m);
        float ls = logf(sum);
        #pragma unroll
        for (int c = 0; c < NC; ++c) out[(size_t)g * NC + c] = y[c] - m - ls;
    }
}

// ---------------- launch ----------------

extern "C" void kernel_launch(void* const* d_in, const int* in_sizes, int n_in,
                              void* d_out, int out_size, void* d_ws, size_t ws_size,
                              hipStream_t stream) {
    const float* x   = (const float*)d_in[0];
    const int*   ei  = (const int*)d_in[1];
    const int*   bat = (const int*)d_in[2];
    const float* w1  = (const float*)d_in[3];
    const float* b1  = (const float*)d_in[4];
    const float* mbg = (const float*)d_in[5];
    const float* mbb = (const float*)d_in[6];
    const float* w2  = (const float*)d_in[7];
    const float* b2  = (const float*)d_in[8];
    const float* bng = (const float*)d_in[9];
    const float* bnb = (const float*)d_in[10];
    const float* fcw = (const float*)d_in[11];
    const float* fcb = (const float*)d_in[12];
    float* out = (float*)d_out;

    ushort* H  = (ushort*)d_ws;
    ushort* Z  = H + (size_t)NN * DD;
    ushort* Y1 = Z + (size_t)NN * DD;
    ushort* WP = Y1 + (size_t)NN * DD;
    float* pooled = (float*)(WP + 8 * 16384);
    float* scsh   = pooled + (size_t)(NL + 1) * NG * DD;
    float* ssum   = scsh + NL * 2 * 2 * DD;
    float* ssq    = ssum + 8 * DD;
    int* deg    = (int*)(ssq + 8 * DD);
    int* rowofs = deg + NN;
    int* part   = rowofs + NN + 1;
    int* cursor = part + 512;
    int* csr    = cursor + NN;

    const int* src = ei;
    const int* dst = ei + NE;
    const int nbN = (NN + 255) / 256;
    const int nbE = (NE + 255) / 256;

    hipLaunchKernelGGL(k_cvtH, dim3(NN * DD / 8 / 256 + 1), dim3(256), 0, stream, x, H);
    hipLaunchKernelGGL(k_zero, dim3(8), dim3(256), 0, stream, ssum, 16 * DD);
    hipLaunchKernelGGL(k_zeroint, dim3(nbN), dim3(256), 0, stream, deg, NN);
    hipLaunchKernelGGL(k_hist, dim3(nbE), dim3(256), 0, stream, dst, deg);
    hipLaunchKernelGGL(k_partial, dim3(nbN), dim3(256), 0, stream, deg, part);
    hipLaunchKernelGGL(k_scanpart, dim3(1), dim3(512), 0, stream, part, nbN);
    hipLaunchKernelGGL(k_exscan, dim3(nbN), dim3(256), 0, stream, deg, part, rowofs);
    hipLaunchKernelGGL(k_copyint, dim3(nbN), dim3(256), 0, stream, rowofs, cursor, NN);
    hipLaunchKernelGGL(k_fill, dim3(nbE), dim3(256), 0, stream, src, dst, cursor, csr);
    hipLaunchKernelGGL(k_wpack, dim3(64), dim3(256), 0, stream, w1, w2, WP);

    const int gmm = (NN + 127) / 128;
    for (int i = 0; i < NL; ++i) {
        float* slot_mlp = scsh + (size_t)(i * 2 + 0) * 2 * DD;
        float* slot_out = scsh + (size_t)(i * 2 + 1) * 2 * DD;
        if (i == 0) {
            hipLaunchKernelGGL((k_pool<false>), dim3(NG), dim3(256), 0, stream, bat, H, pooled, (const float*)nullptr);
            hipLaunchKernelGGL((k_gather<false>), dim3(NN / 16), dim3(256), 0, stream, rowofs, csr, H, Z, (const float*)nullptr);
        } else {
            const float* bnp = scsh + (size_t)((i - 1) * 2 + 1) * 2 * DD;
            hipLaunchKernelGGL((k_pool<true>), dim3(NG), dim3(256), 0, stream, bat, H, pooled + (size_t)i * NG * DD, bnp);
            hipLaunchKernelGGL((k_gather<true>), dim3(NN / 16), dim3(256), 0, stream, rowofs, csr, H, Z, bnp);
        }
        hipLaunchKernelGGL((k_mm<false>), dim3(gmm), dim3(256), 0, stream,
                           Z, WP + (size_t)i * 16384, b1 + (size_t)i * DD, (const float*)nullptr, Y1, ssum, ssq);
        hipLaunchKernelGGL(k_finstats, dim3(1), dim3(DD), 0, stream, ssum, ssq, slot_mlp, mbg + (size_t)i * DD, mbb + (size_t)i * DD);
        hipLaunchKernelGGL((k_mm<true>), dim3(gmm), dim3(256), 0, stream,
                           Y1, WP + (size_t)(4 + i) * 16384, b2 + (size_t)i * DD, slot_mlp, H, ssum, ssq);
        hipLaunchKernelGGL(k_finstats, dim3(1), dim3(DD), 0, stream, ssum, ssq, slot_out, bng + (size_t)i * DD, bnb + (size_t)i * DD);
    }
    hipLaunchKernelGGL((k_pool<true>), dim3(NG), dim3(256), 0, stream, bat, H,
                       pooled + (size_t)NL * NG * DD, scsh + (size_t)(3 * 2 + 1) * 2 * DD);
    hipLaunchKernelGGL(k_readout, dim3(NG), dim3(64), 0, stream, pooled, fcw, fcb, out);
}

// Round 5
// 453.513 us; speedup vs baseline: 11.0215x; 1.0644x over previous
//
#include <hip/hip_runtime.h>

#define NN 100000
#define NE 600000
#define DD 128
#define NG 512
#define NC 10
#define NL 4

typedef __attribute__((ext_vector_type(8))) short short8;
typedef __attribute__((ext_vector_type(4))) float f32x4;

__device__ __forceinline__ float b2f(unsigned int u) { return __uint_as_float(u << 16); }
__device__ __forceinline__ unsigned int f2b(float f) {
    unsigned int u = __float_as_uint(f);
    return (u + 0x7fffu + ((u >> 16) & 1u)) >> 16;  // RNE
}
__device__ __forceinline__ void unpack8(uint4 v, float* f) {
    f[0] = b2f(v.x & 0xffffu); f[1] = b2f(v.x >> 16);
    f[2] = b2f(v.y & 0xffffu); f[3] = b2f(v.y >> 16);
    f[4] = b2f(v.z & 0xffffu); f[5] = b2f(v.z >> 16);
    f[6] = b2f(v.w & 0xffffu); f[7] = b2f(v.w >> 16);
}
__device__ __forceinline__ uint4 pack8(const float* f) {
    uint4 v;
    v.x = f2b(f[0]) | (f2b(f[1]) << 16);
    v.y = f2b(f[2]) | (f2b(f[3]) << 16);
    v.z = f2b(f[4]) | (f2b(f[5]) << 16);
    v.w = f2b(f[6]) | (f2b(f[7]) << 16);
    return v;
}

// ---------------- utility ----------------

__global__ __launch_bounds__(256) void k_zero(float* __restrict__ p, int n) {
    int i = blockIdx.x * 256 + threadIdx.x;
    if (i < n) p[i] = 0.f;
}
__global__ __launch_bounds__(256) void k_zeroint(int* __restrict__ p, int n) {
    int i = blockIdx.x * 256 + threadIdx.x;
    if (i < n) p[i] = 0;
}
__global__ __launch_bounds__(256) void k_copyint(const int* __restrict__ s, int* __restrict__ d, int n) {
    int i = blockIdx.x * 256 + threadIdx.x;
    if (i < n) d[i] = s[i];
}

// x (fp32) -> H (bf16)
__global__ __launch_bounds__(256) void k_cvtH(const float* __restrict__ x, ushort* __restrict__ h) {
    int i = blockIdx.x * 256 + threadIdx.x;  // one per 8 elems
    if (i >= NN * DD / 8) return;
    float4 a = ((const float4*)x)[2 * i], b = ((const float4*)x)[2 * i + 1];
    float f[8] = {a.x, a.y, a.z, a.w, b.x, b.y, b.z, b.w};
    ((uint4*)h)[i] = pack8(f);
}

// pack W (fp32 row-major [k][c]) into MFMA fragment order, bf16.
// frag v&15 -> col, v>>4 -> k-octet; used as the (swapped) A-operand.
__global__ __launch_bounds__(256) void k_wpack(const float* __restrict__ w1, const float* __restrict__ w2,
                                               ushort* __restrict__ wp) {
    int id = blockIdx.x * 256 + threadIdx.x;  // 16384 total
    int v = id & 63;
    int kc = (id >> 6) & 3;
    int ct = (id >> 8) & 7;
    int m = id >> 11;
    const float* W = (m < 4) ? (w1 + (size_t)m * DD * DD) : (w2 + (size_t)(m - 4) * DD * DD);
    int c = ct * 16 + (v & 15);
    int kbase = kc * 32 + ((v >> 4) << 3);
    ushort* dst = wp + ((size_t)id << 3);
    #pragma unroll
    for (int j = 0; j < 8; ++j) dst[j] = (ushort)f2b(W[(size_t)(kbase + j) * DD + c]);
}

// ---------------- CSR build ----------------

__global__ __launch_bounds__(256) void k_hist(const int* __restrict__ dst, int* __restrict__ deg) {
    int e = blockIdx.x * 256 + threadIdx.x;
    if (e < NE) atomicAdd(&deg[dst[e]], 1);
}
__global__ __launch_bounds__(256) void k_partial(const int* __restrict__ deg, int* __restrict__ part) {
    __shared__ int s[256];
    int t = threadIdx.x;
    int i = blockIdx.x * 256 + t;
    s[t] = (i < NN) ? deg[i] : 0;
    __syncthreads();
    #pragma unroll
    for (int off = 128; off >= 1; off >>= 1) {
        if (t < off) s[t] += s[t + off];
        __syncthreads();
    }
    if (t == 0) part[blockIdx.x] = s[0];
}
__global__ __launch_bounds__(512) void k_scanpart(int* __restrict__ part, int nb) {
    __shared__ int s[512];
    int t = threadIdx.x;
    int v = (t < nb) ? part[t] : 0;
    s[t] = v;
    __syncthreads();
    #pragma unroll
    for (int off = 1; off < 512; off <<= 1) {
        int add = (t >= off) ? s[t - off] : 0;
        __syncthreads();
        s[t] += add;
        __syncthreads();
    }
    if (t < nb) part[t] = s[t] - v;
}
__global__ __launch_bounds__(256) void k_exscan(const int* __restrict__ deg, const int* __restrict__ part,
                                                int* __restrict__ rowofs) {
    __shared__ int s[256];
    int b = blockIdx.x, t = threadIdx.x;
    int i = b * 256 + t;
    int v = (i < NN) ? deg[i] : 0;
    s[t] = v;
    __syncthreads();
    #pragma unroll
    for (int off = 1; off < 256; off <<= 1) {
        int add = (t >= off) ? s[t - off] : 0;
        __syncthreads();
        s[t] += add;
        __syncthreads();
    }
    if (i < NN) rowofs[i] = part[b] + s[t] - v;
    if (i == NN - 1) rowofs[NN] = part[b] + s[t];
}
__global__ __launch_bounds__(256) void k_fill(const int* __restrict__ src, const int* __restrict__ dst,
                                              int* __restrict__ cursor, int* __restrict__ csr) {
    int e = blockIdx.x * 256 + threadIdx.x;
    if (e >= NE) return;
    int d = dst[e];
    int pos = atomicAdd(&cursor[d], 1);
    csr[pos] = src[e];
}

// ---------------- gather (bf16, optional fused BN+ReLU on load) ----------------
template<bool BN>
__global__ __launch_bounds__(256) void k_gather(const int* __restrict__ rowofs, const int* __restrict__ csr,
                                                const ushort* __restrict__ h, ushort* __restrict__ z,
                                                const float* __restrict__ scsh) {
    int t = threadIdx.x;
    int n = blockIdx.x * 16 + (t >> 4);
    int cl = t & 15;
    int cb = cl * 8;
    float sc[8], sh[8];
    if (BN) {
        #pragma unroll
        for (int j = 0; j < 8; ++j) { sc[j] = scsh[cb + j]; sh[j] = scsh[DD + cb + j]; }
    }
    float acc[8], f[8];
    uint4 v = ((const uint4*)h)[(size_t)n * 16 + cl];
    unpack8(v, f);
    #pragma unroll
    for (int j = 0; j < 8; ++j)
        acc[j] = BN ? fmaxf(fmaf(f[j], sc[j], sh[j]), 0.f) : f[j];
    int start = rowofs[n], end = rowofs[n + 1];
    for (int e = start; e < end; ++e) {
        int s = csr[e];
        v = ((const uint4*)h)[(size_t)s * 16 + cl];
        unpack8(v, f);
        #pragma unroll
        for (int j = 0; j < 8; ++j)
            acc[j] += BN ? fmaxf(fmaf(f[j], sc[j], sh[j]), 0.f) : f[j];
    }
    ((uint4*)z)[(size_t)n * 16 + cl] = pack8(acc);
}

// ---------------- MFMA GEMM (64-row tile, swapped operands) ----------------
// block: 256 thr = 4 waves (2 row x 2 col). Tile 64x128, K=128, grid 1563.
// D = mfma(Wfrag, Zfrag): lane holds 4 consecutive out-cols of one row
// -> vectorized uint2 epilogue. Stats computed in the store loop + LDS tree.
template<bool TRANS>
__global__ __launch_bounds__(256, 4) void k_mm(const ushort* __restrict__ in, const ushort* __restrict__ wp,
                                               const float* __restrict__ bias, const float* __restrict__ scsh,
                                               ushort* __restrict__ outp,
                                               float* __restrict__ ssum, float* __restrict__ ssq) {
    __shared__ __align__(16) char lds[16384];
    const int t = threadIdx.x;
    const int lane = t & 63;
    const int wid = t >> 6;
    const int wr = wid >> 1, wc = wid & 1;   // wave: 32 rows x 64 cols
    const int rb = blockIdx.x * 64;
    const int rep = blockIdx.x & 7;

    // stage A (Z) tile -> LDS, swizzled; 64 rows x 16 chunks, 4 iters
    float scv[8], shv[8];
    if (TRANS) {
        int cb = (t & 15) * 8;
        #pragma unroll
        for (int j = 0; j < 8; ++j) { scv[j] = scsh[cb + j]; shv[j] = scsh[DD + cb + j]; }
    }
    #pragma unroll
    for (int i = 0; i < 4; ++i) {
        int c = i * 256 + t;
        int row = c >> 4;
        int g = rb + row;
        uint4 v = make_uint4(0, 0, 0, 0);
        if (g < NN) {
            v = *((const uint4*)in + (size_t)g * 16 + (c & 15));
            if (TRANS) {
                float f[8];
                unpack8(v, f);
                #pragma unroll
                for (int j = 0; j < 8; ++j) f[j] = fmaxf(fmaf(f[j], scv[j], shv[j]), 0.f);
                v = pack8(f);
            }
        }
        *(uint4*)(lds + ((c * 16) ^ ((row & 7) << 4))) = v;
    }
    __syncthreads();

    f32x4 acc[2][4];
    #pragma unroll
    for (int rt = 0; rt < 2; ++rt)
        #pragma unroll
        for (int ct = 0; ct < 4; ++ct) acc[rt][ct] = (f32x4){0.f, 0.f, 0.f, 0.f};

    #pragma unroll
    for (int kc = 0; kc < 4; ++kc) {
        // W fragments for this k-slab only (16 regs live)
        short8 wf[4];
        #pragma unroll
        for (int ct = 0; ct < 4; ++ct)
            wf[ct] = *(const short8*)(wp + (size_t)((((wc * 4 + ct) * 4 + kc) * 64 + lane) << 3));
        #pragma unroll
        for (int rt = 0; rt < 2; ++rt) {
            int row = wr * 32 + rt * 16 + (lane & 15);
            int off = (row * 256 + ((kc * 32 + ((lane >> 4) << 3)) << 1)) ^ ((row & 7) << 4);
            short8 zf = *(const short8*)(lds + off);
            #pragma unroll
            for (int ct = 0; ct < 4; ++ct)
                acc[rt][ct] = __builtin_amdgcn_mfma_f32_16x16x32_bf16(wf[ct], zf, acc[rt][ct], 0, 0, 0);
        }
    }
    __syncthreads();

    // epilogue: lane holds rows wr*32+rt*16+(lane&15), cols wc*64+ct*16+(lane>>4)*4+r
    const int zr = lane & 15, cq = lane >> 4;
    #pragma unroll
    for (int rt = 0; rt < 2; ++rt) {
        int row = wr * 32 + rt * 16 + zr;
        #pragma unroll
        for (int ct = 0; ct < 4; ++ct) {
            int c0 = wc * 64 + ct * 16 + cq * 4;
            float4 bi = *(const float4*)(bias + c0);
            f32x4 a = acc[rt][ct];
            float v0 = a[0] + bi.x, v1 = a[1] + bi.y, v2 = a[2] + bi.z, v3 = a[3] + bi.w;
            uint2 pk;
            pk.x = f2b(v0) | (f2b(v1) << 16);
            pk.y = f2b(v2) | (f2b(v3) << 16);
            *(uint2*)(lds + ((row * 256 + c0 * 2) ^ ((row & 7) << 4))) = pk;
        }
    }
    __syncthreads();

    // store + column stats from the bf16 tile
    float s8[8], q8[8];
    #pragma unroll
    for (int j = 0; j < 8; ++j) { s8[j] = 0.f; q8[j] = 0.f; }
    #pragma unroll
    for (int i = 0; i < 4; ++i) {
        int c = i * 256 + t;
        int row = c >> 4;
        int g = rb + row;
        if (g < NN) {
            uint4 v = *(const uint4*)(lds + ((c * 16) ^ ((row & 7) << 4)));
            ((uint4*)outp)[(size_t)g * 16 + (c & 15)] = v;
            float f[8];
            unpack8(v, f);
            #pragma unroll
            for (int j = 0; j < 8; ++j) { s8[j] += f[j]; q8[j] += f[j] * f[j]; }
        }
    }
    __syncthreads();
    float* rs = (float*)lds;            // 16 x 128
    float* rq = rs + 16 * DD;           // 16 x 128
    const int slot = t >> 4, cb2 = (t & 15) * 8;
    #pragma unroll
    for (int j = 0; j < 8; j += 4) {
        *(float4*)(rs + slot * DD + cb2 + j) = make_float4(s8[j], s8[j + 1], s8[j + 2], s8[j + 3]);
        *(float4*)(rq + slot * DD + cb2 + j) = make_float4(q8[j], q8[j + 1], q8[j + 2], q8[j + 3]);
    }
    __syncthreads();
    #pragma unroll
    for (int off = 8; off >= 1; off >>= 1) {
        if (slot < off) {
            #pragma unroll
            for (int j = 0; j < 8; j += 4) {
                float4 a = *(float4*)(rs + slot * DD + cb2 + j);
                float4 b = *(float4*)(rs + (slot + off) * DD + cb2 + j);
                a.x += b.x; a.y += b.y; a.z += b.z; a.w += b.w;
                *(float4*)(rs + slot * DD + cb2 + j) = a;
                float4 c2 = *(float4*)(rq + slot * DD + cb2 + j);
                float4 d  = *(float4*)(rq + (slot + off) * DD + cb2 + j);
                c2.x += d.x; c2.y += d.y; c2.z += d.z; c2.w += d.w;
                *(float4*)(rq + slot * DD + cb2 + j) = c2;
            }
        }
        __syncthreads();
    }
    if (t < DD) {
        atomicAdd(ssum + rep * DD + t, rs[t]);
        atomicAdd(ssq + rep * DD + t, rq[t]);
    }
}

// ---------------- BN stats -> (scale, shift), re-zero replicas ----------------
__global__ __launch_bounds__(DD) void k_finstats(float* __restrict__ ssum, float* __restrict__ ssq,
                                                 float* __restrict__ dst,
                                                 const float* __restrict__ g, const float* __restrict__ b) {
    int t = threadIdx.x;
    float s = 0.f, q = 0.f;
    #pragma unroll
    for (int r = 0; r < 8; ++r) {
        s += ssum[r * DD + t]; q += ssq[r * DD + t];
        ssum[r * DD + t] = 0.f; ssq[r * DD + t] = 0.f;
    }
    const float invn = 1.0f / NN;
    float m = s * invn;
    float var = q * invn - m * m;
    float sc = g[t] * rsqrtf(var + 1e-5f);
    dst[t] = sc;
    dst[DD + t] = b[t] - m * sc;
}

// ---------------- per-graph pooling: vectorized, 16 lanes x 16 row-slots ----------------
__device__ __forceinline__ int lowerb(const int* __restrict__ a, int n, int key) {
    int lo = 0, hi = n;
    while (lo < hi) {
        int mid = (lo + hi) >> 1;
        if (a[mid] < key) lo = mid + 1; else hi = mid;
    }
    return lo;
}

template<bool BN>
__global__ __launch_bounds__(256) void k_pool(const int* __restrict__ batch, const ushort* __restrict__ h,
                                              float* __restrict__ pooled, const float* __restrict__ scsh) {
    int g = blockIdx.x;
    int t = threadIdx.x;
    int cl = t & 15;
    int rs = t >> 4;
    int cb = cl * 8;
    float sc[8], sh[8];
    if (BN) {
        #pragma unroll
        for (int j = 0; j < 8; ++j) { sc[j] = scsh[cb + j]; sh[j] = scsh[DD + cb + j]; }
    }
    int start = lowerb(batch, NN, g);
    int end = lowerb(batch, NN, g + 1);
    float acc[8];
    #pragma unroll
    for (int j = 0; j < 8; ++j) acc[j] = 0.f;
    for (int n = start + rs; n < end; n += 16) {
        uint4 v = ((const uint4*)h)[(size_t)n * 16 + cl];
        float f[8];
        unpack8(v, f);
        #pragma unroll
        for (int j = 0; j < 8; ++j)
            acc[j] += BN ? fmaxf(fmaf(f[j], sc[j], sh[j]), 0.f) : f[j];
    }
    __shared__ float red[16 * DD];
    #pragma unroll
    for (int j = 0; j < 8; j += 4)
        *(float4*)(red + rs * DD + cb + j) = make_float4(acc[j], acc[j + 1], acc[j + 2], acc[j + 3]);
    __syncthreads();
    #pragma unroll
    for (int off = 8; off >= 1; off >>= 1) {
        if (rs < off) {
            #pragma unroll
            for (int j = 0; j < 8; j += 4) {
                float4 a = *(float4*)(red + rs * DD + cb + j);
                float4 b = *(float4*)(red + (rs + off) * DD + cb + j);
                a.x += b.x; a.y += b.y; a.z += b.z; a.w += b.w;
                *(float4*)(red + rs * DD + cb + j) = a;
            }
        }
        __syncthreads();
    }
    if (rs == 0) {
        #pragma unroll
        for (int j = 0; j < 8; j += 4)
            *(float4*)(pooled + (size_t)g * DD + cb + j) = *(float4*)(red + cb + j);
    }
}

// ---------------- readout ----------------
__global__ __launch_bounds__(64) void k_readout(const float* __restrict__ pooled, const float* __restrict__ fcw,
                                                const float* __restrict__ fcb, float* __restrict__ out) {
    int g = blockIdx.x, t = threadIdx.x;
    float part[NC];
    #pragma unroll
    for (int c = 0; c < NC; ++c) part[c] = 0.f;
    for (int i = 0; i < NL + 1; ++i) {
        #pragma unroll
        for (int hh = 0; hh < 2; ++hh) {
            int d = t + (hh << 6);
            float v = pooled[((size_t)i * NG + g) * DD + d];
            const float* wr = fcw + ((size_t)i * DD + d) * NC;
            #pragma unroll
            for (int c = 0; c < NC; ++c) part[c] = fmaf(v, wr[c], part[c]);
        }
    }
    #pragma unroll
    for (int off = 32; off >= 1; off >>= 1) {
        #pragma unroll
        for (int c = 0; c < NC; ++c) part[c] += __shfl_down(part[c], off);
    }
    if (t == 0) {
        float y[NC];
        #pragma unroll
        for (int c = 0; c < NC; ++c) {
            float bs = 0.f;
            for (int i = 0; i < NL + 1; ++i) bs += fcb[i * NC + c];
            y[c] = part[c] + bs;
        }
        float m = y[0];
        #pragma unroll
        for (int c = 1; c < NC; ++c) m = fmaxf(m, y[c]);
        float sum = 0.f;
        #pragma unroll
        for (int c = 0; c < NC; ++c) sum += expf(y[c] - m);
        float ls = logf(sum);
        #pragma unroll
        for (int c = 0; c < NC; ++c) out[(size_t)g * NC + c] = y[c] - m - ls;
    }
}

// ---------------- launch ----------------

extern "C" void kernel_launch(void* const* d_in, const int* in_sizes, int n_in,
                              void* d_out, int out_size, void* d_ws, size_t ws_size,
                              hipStream_t stream) {
    const float* x   = (const float*)d_in[0];
    const int*   ei  = (const int*)d_in[1];
    const int*   bat = (const int*)d_in[2];
    const float* w1  = (const float*)d_in[3];
    const float* b1  = (const float*)d_in[4];
    const float* mbg = (const float*)d_in[5];
    const float* mbb = (const float*)d_in[6];
    const float* w2  = (const float*)d_in[7];
    const float* b2  = (const float*)d_in[8];
    const float* bng = (const float*)d_in[9];
    const float* bnb = (const float*)d_in[10];
    const float* fcw = (const float*)d_in[11];
    const float* fcb = (const float*)d_in[12];
    float* out = (float*)d_out;

    ushort* H  = (ushort*)d_ws;
    ushort* Z  = H + (size_t)NN * DD;
    ushort* Y1 = Z + (size_t)NN * DD;
    ushort* WP = Y1 + (size_t)NN * DD;
    float* pooled = (float*)(WP + 8 * 16384);
    float* scsh   = pooled + (size_t)(NL + 1) * NG * DD;
    float* ssum   = scsh + NL * 2 * 2 * DD;
    float* ssq    = ssum + 8 * DD;
    int* deg    = (int*)(ssq + 8 * DD);
    int* rowofs = deg + NN;
    int* part   = rowofs + NN + 1;
    int* cursor = part + 512;
    int* csr    = cursor + NN;

    const int* src = ei;
    const int* dst = ei + NE;
    const int nbN = (NN + 255) / 256;
    const int nbE = (NE + 255) / 256;

    hipLaunchKernelGGL(k_cvtH, dim3(NN * DD / 8 / 256 + 1), dim3(256), 0, stream, x, H);
    hipLaunchKernelGGL(k_zero, dim3(8), dim3(256), 0, stream, ssum, 16 * DD);
    hipLaunchKernelGGL(k_zeroint, dim3(nbN), dim3(256), 0, stream, deg, NN);
    hipLaunchKernelGGL(k_hist, dim3(nbE), dim3(256), 0, stream, dst, deg);
    hipLaunchKernelGGL(k_partial, dim3(nbN), dim3(256), 0, stream, deg, part);
    hipLaunchKernelGGL(k_scanpart, dim3(1), dim3(512), 0, stream, part, nbN);
    hipLaunchKernelGGL(k_exscan, dim3(nbN), dim3(256), 0, stream, deg, part, rowofs);
    hipLaunchKernelGGL(k_copyint, dim3(nbN), dim3(256), 0, stream, rowofs, cursor, NN);
    hipLaunchKernelGGL(k_fill, dim3(nbE), dim3(256), 0, stream, src, dst, cursor, csr);
    hipLaunchKernelGGL(k_wpack, dim3(64), dim3(256), 0, stream, w1, w2, WP);

    const int gmm = (NN + 63) / 64;  // 1563
    for (int i = 0; i < NL; ++i) {
        float* slot_mlp = scsh + (size_t)(i * 2 + 0) * 2 * DD;
        float* slot_out = scsh + (size_t)(i * 2 + 1) * 2 * DD;
        if (i == 0) {
            hipLaunchKernelGGL((k_pool<false>), dim3(NG), dim3(256), 0, stream, bat, H, pooled, (const float*)nullptr);
            hipLaunchKernelGGL((k_gather<false>), dim3(NN / 16), dim3(256), 0, stream, rowofs, csr, H, Z, (const float*)nullptr);
        } else {
            const float* bnp = scsh + (size_t)((i - 1) * 2 + 1) * 2 * DD;
            hipLaunchKernelGGL((k_pool<true>), dim3(NG), dim3(256), 0, stream, bat, H, pooled + (size_t)i * NG * DD, bnp);
            hipLaunchKernelGGL((k_gather<true>), dim3(NN / 16), dim3(256), 0, stream, rowofs, csr, H, Z, bnp);
        }
        hipLaunchKernelGGL((k_mm<false>), dim3(gmm), dim3(256), 0, stream,
                           Z, WP + (size_t)i * 16384, b1 + (size_t)i * DD, (const float*)nullptr, Y1, ssum, ssq);
        hipLaunchKernelGGL(k_finstats, dim3(1), dim3(DD), 0, stream, ssum, ssq, slot_mlp, mbg + (size_t)i * DD, mbb + (size_t)i * DD);
        hipLaunchKernelGGL((k_mm<true>), dim3(gmm), dim3(256), 0, stream,
                           Y1, WP + (size_t)(4 + i) * 16384, b2 + (size_t)i * DD, slot_mlp, H, ssum, ssq);
        hipLaunchKernelGGL(k_finstats, dim3(1), dim3(DD), 0, stream, ssum, ssq, slot_out, bng + (size_t)i * DD, bnb + (size_t)i * DD);
    }
    hipLaunchKernelGGL((k_pool<true>), dim3(NG), dim3(256), 0, stream, bat, H,
                       pooled + (size_t)NL * NG * DD, scsh + (size_t)(3 * 2 + 1) * 2 * DD);
    hipLaunchKernelGGL(k_readout, dim3(NG), dim3(64), 0, stream, pooled, fcw, fcb, out);
}